// Round 5
// baseline (6435.468 us; speedup 1.0000x reference)
//
#include <hip/hip_runtime.h>
#include <math.h>

// Problem constants (match reference)
#define N_PTS   192000
#define NPATCH  4000      // N/48
#define PK      48        // patch size
#define NH      4         // heads
#define HD      16        // head dim

// Inline erf (Abramowitz & Stegun 7.1.26, |eps| <= 1.5e-7), no libm call.
__device__ __forceinline__ float erf_inl(float x) {
    float ax = fabsf(x);
    float t = 1.0f / fmaf(0.3275911f, ax, 1.0f);
    float poly = fmaf(1.061405429f, t, -1.453152027f);
    poly = fmaf(poly, t, 1.421413741f);
    poly = fmaf(poly, t, -0.284496736f);
    poly = fmaf(poly, t, 0.254829592f);
    poly *= t;
    float e = __expf(-ax * ax);          // native v_exp_f32
    float r = 1.0f - poly * e;
    return copysignf(r, x);
}

__device__ __forceinline__ float gelu_exact(float x) {
    return 0.5f * x * (1.0f + erf_inl(x * 0.70710678118654752f));
}

#define FMA4(acc, base, w) do { \
    (acc)[(base)+0] = fmaf(vv, (w).x, (acc)[(base)+0]); \
    (acc)[(base)+1] = fmaf(vv, (w).y, (acc)[(base)+1]); \
    (acc)[(base)+2] = fmaf(vv, (w).z, (acc)[(base)+2]); \
    (acc)[(base)+3] = fmaf(vv, (w).w, (acc)[(base)+3]); } while (0)

// ---------------------------------------------------------------------------
// K1: 1 lane = 1 point. softmax(seg)+coord -> feat -> LN1 -> qkv.
// W_in staged once in LDS; W_qkv in double-buffered [64][16] chunks with
// global prefetch overlapped with the FMA phase. Uniform ds_read_b128
// broadcasts, zero bank conflicts.  (Unchanged from R3 — audited correct.)
// ---------------------------------------------------------------------------
__global__ __launch_bounds__(256, 3) void k_in_qkv(
    const float* __restrict__ seg, const float* __restrict__ coord,
    const float* __restrict__ W_in, const float* __restrict__ b_in,
    const float* __restrict__ g1, const float* __restrict__ be1,
    const float* __restrict__ W_qkv, const float* __restrict__ b_qkv,
    float* __restrict__ feat_out, float* __restrict__ qkv_out)
{
    __shared__ float sWin[23 * 64];      // 5.75 KB, staged once
    __shared__ float sWq[2][64][16];     // 8 KB, double-buffered chunks

    int tid = threadIdx.x;
    int i = blockIdx.x * 256 + tid;      // grid exact: 750*256 = N

    // prologue staging (linear float4 writes -> conflict-free)
    {
        const float4* s1 = (const float4*)W_in;
        float4* d1 = (float4*)sWin;
        for (int u = tid; u < 368; u += 256) d1[u] = s1[u];
        int c = tid >> 2, t4 = tid & 3;  // addr = tid*4 floats (linear)
        *(float4*)&sWq[0][c][t4 * 4] =
            *(const float4*)(W_qkv + (size_t)c * 192 + t4 * 4);
    }
    __syncthreads();

    // softmax(seg,20) + coord
    float iv[23];
    {
        const float* s = seg + (size_t)i * 20;
        float mx = -1e30f;
        #pragma unroll
        for (int j = 0; j < 20; ++j) { iv[j] = s[j]; mx = fmaxf(mx, iv[j]); }
        float sum = 0.f;
        #pragma unroll
        for (int j = 0; j < 20; ++j) { iv[j] = __expf(iv[j] - mx); sum += iv[j]; }
        float r = 1.f / sum;
        #pragma unroll
        for (int j = 0; j < 20; ++j) iv[j] *= r;
        iv[20] = coord[(size_t)i*3 + 0];
        iv[21] = coord[(size_t)i*3 + 1];
        iv[22] = coord[(size_t)i*3 + 2];
    }

    // feat = iv @ W_in + b_in (weights broadcast from LDS)
    float f[64];
    #pragma unroll
    for (int c = 0; c < 64; ++c) f[c] = b_in[c];
    #pragma unroll
    for (int j = 0; j < 23; ++j) {
        float vv = iv[j];
        #pragma unroll
        for (int c4 = 0; c4 < 16; ++c4) {
            float4 w = *(const float4*)&sWin[j*64 + c4*4];
            FMA4(f, c4*4, w);
        }
    }
    {   // store feat
        float4* fd = (float4*)(feat_out + (size_t)i * 64);
        #pragma unroll
        for (int c4 = 0; c4 < 16; ++c4)
            fd[c4] = make_float4(f[4*c4], f[4*c4+1], f[4*c4+2], f[4*c4+3]);
    }
    // LN1 in place
    {
        float m = 0.f;
        #pragma unroll
        for (int c = 0; c < 64; ++c) m += f[c];
        m *= (1.f/64.f);
        float v = 0.f;
        #pragma unroll
        for (int c = 0; c < 64; ++c) { float d = f[c]-m; v = fmaf(d, d, v); }
        v *= (1.f/64.f);
        float rs = 1.f / sqrtf(v + 1e-5f);
        #pragma unroll
        for (int c = 0; c < 64; ++c) f[c] = (f[c]-m)*rs*g1[c] + be1[c];
    }
    // qkv in 12 chunks of 16 outputs, double-buffered weight staging
    int cur = 0;
    int sc = tid >> 2, st4 = tid & 3;
    for (int ch = 0; ch < 12; ++ch) {
        bool have = (ch + 1 < 12);
        float4 nw;
        if (have)
            nw = *(const float4*)(W_qkv + (size_t)sc*192 + (ch+1)*16 + st4*4);
        float a[16];
        #pragma unroll
        for (int t = 0; t < 16; ++t) a[t] = b_qkv[ch*16 + t];
        #pragma unroll
        for (int c = 0; c < 64; ++c) {
            float vv = f[c];
            #pragma unroll
            for (int q = 0; q < 4; ++q) {
                float4 w = *(const float4*)&sWq[cur][c][q*4];
                FMA4(a, q*4, w);
            }
        }
        float4* qd = (float4*)(qkv_out + (size_t)i * 192 + ch*16);
        #pragma unroll
        for (int q = 0; q < 4; ++q)
            qd[q] = make_float4(a[4*q], a[4*q+1], a[4*q+2], a[4*q+3]);
        __syncthreads();
        if (have) *(float4*)&sWq[cur ^ 1][sc][st4 * 4] = nw;
        __syncthreads();
        cur ^= 1;
    }
}

// ---------------------------------------------------------------------------
// K2: windowed attention — UNCHANGED from validated R2 version.
// ---------------------------------------------------------------------------
__global__ __launch_bounds__(256) void k_attn(
    const float* __restrict__ qkv, const int* __restrict__ order,
    const int* __restrict__ grid_coord, const float* __restrict__ rpe,
    float* __restrict__ outb)
{
    __shared__ float q_s[NH][PK][17];
    __shared__ float k_s[NH][PK][HD];
    __shared__ float v_s[NH][PK][HD];
    __shared__ float rpe_s[276];
    __shared__ int   ord_s[PK];
    __shared__ int   gc_s[PK][3];

    int p = blockIdx.x;
    int tid = threadIdx.x;

    if (tid < PK) ord_s[tid] = order[p*PK + tid];
    for (int t = tid; t < 276; t += 256) rpe_s[t] = rpe[t];
    __syncthreads();

    if (tid < PK) {
        int row = ord_s[tid];
        gc_s[tid][0] = grid_coord[(size_t)row*3 + 0];
        gc_s[tid][1] = grid_coord[(size_t)row*3 + 1];
        gc_s[tid][2] = grid_coord[(size_t)row*3 + 2];
    }
    {
        int lane = tid & 63;
        int hh = lane >> 4, dd = lane & 15;
        for (int rr = tid >> 6; rr < PK; rr += 4) {
            const float* src = qkv + (size_t)ord_s[rr] * 192;
            float qv = src[lane];
            float kv = src[64 + lane];
            float vv = src[128 + lane];
            q_s[hh][rr][dd] = qv;
            k_s[hh][rr][dd] = kv;
            v_s[hh][rr][dd] = vv;
        }
    }
    __syncthreads();

    int h = tid >> 6;
    int r = tid & 63;
    if (r >= PK) return;

    float qr[HD];
    #pragma unroll
    for (int d = 0; d < HD; ++d) qr[d] = q_s[h][r][d];
    int gx = gc_s[r][0], gy = gc_s[r][1], gz = gc_s[r][2];

    float s[PK];
    #pragma unroll 4
    for (int m = 0; m < PK; ++m) {
        float a = 0.f;
        #pragma unroll
        for (int d = 0; d < HD; ++d) a = fmaf(qr[d], k_s[h][m][d], a);
        a *= 0.25f;
        int i0 = min(max(gx - gc_s[m][0], -11), 11) + 11;
        int i1 = min(max(gy - gc_s[m][1], -11), 11) + 34;
        int i2 = min(max(gz - gc_s[m][2], -11), 11) + 57;
        a += rpe_s[i0*4 + h] + rpe_s[i1*4 + h] + rpe_s[i2*4 + h];
        s[m] = a;
    }

    float mx = -1e30f;
    #pragma unroll
    for (int m = 0; m < PK; ++m) mx = fmaxf(mx, s[m]);
    float sum = 0.f;
    #pragma unroll
    for (int m = 0; m < PK; ++m) { s[m] = __expf(s[m] - mx); sum += s[m]; }
    float rinv = 1.f / sum;

    float acc[HD];
    #pragma unroll
    for (int d = 0; d < HD; ++d) acc[d] = 0.f;
    #pragma unroll 4
    for (int m = 0; m < PK; ++m) {
        float pv = s[m] * rinv;
        #pragma unroll
        for (int d = 0; d < HD; ++d) acc[d] = fmaf(pv, v_s[h][m][d], acc[d]);
    }
    {
        float* dst = outb + (size_t)ord_s[r]*64 + h*HD;
        float4* d4 = (float4*)dst;
        #pragma unroll
        for (int d4i = 0; d4i < 4; ++d4i)
            d4[d4i] = make_float4(acc[4*d4i], acc[4*d4i+1], acc[4*d4i+2], acc[4*d4i+3]);
    }
}

// ---------------------------------------------------------------------------
// K3: 1 lane = 1 point. attn proj + residual + LN2 + FFN + head.
// R2-validated dataflow (hh[64] computed once, read-only in the chunk loop;
// f[64] is the FFN accumulator) + LDS-staged weights:
//   sWa (W_attn) and sH1 (W_h1) staged once; W_f1/W_f2 in double-buffered
//   16-hidden-unit chunks, global prefetch overlapped with FMA phase.
// ---------------------------------------------------------------------------
__global__ __launch_bounds__(256, 3) void k_ffn(
    const float* __restrict__ outb, const float* __restrict__ featb,
    const float* __restrict__ W_attn, const float* __restrict__ b_attn,
    const float* __restrict__ g2, const float* __restrict__ be2,
    const float* __restrict__ W_f1, const float* __restrict__ b_f1,
    const float* __restrict__ W_f2, const float* __restrict__ b_f2,
    const float* __restrict__ W_h1, const float* __restrict__ b_h1,
    const float* __restrict__ W_h2, const float* __restrict__ b_h2,
    float* __restrict__ out)
{
    __shared__ float sWa[64 * 64];       // 16 KB, W_attn staged once
    __shared__ float sH1[64 * 32];       // 8 KB,  W_h1 staged once
    __shared__ float sW1[2][64][16];     // 8 KB,  W_f1 chunks (raw)
    __shared__ float sW2[2][16][64];     // 8 KB,  W_f2 chunks

    int tid = threadIdx.x;
    int i = blockIdx.x * 256 + tid;
    int sc = tid >> 2, st4 = tid & 3;    // W_f1 stager coords (addr = tid*4)
    int stt = tid >> 4, sc4 = tid & 15;  // W_f2 stager coords (addr = tid*4)

    // ---- prologue: stage sWa, sH1, chunk 0 of W_f1/W_f2 ----
    {
        const float4* s1 = (const float4*)W_attn;
        float4* d1 = (float4*)sWa;
        for (int u = tid; u < 1024; u += 256) d1[u] = s1[u];
        const float4* s2 = (const float4*)W_h1;
        float4* d2 = (float4*)sH1;
        for (int u = tid; u < 512; u += 256) d2[u] = s2[u];
        *(float4*)&sW1[0][sc][st4*4] =
            *(const float4*)(W_f1 + (size_t)sc*256 + st4*4);
        *(float4*)&sW2[0][stt][sc4*4] =
            *(const float4*)(W_f2 + (size_t)stt*64 + sc4*4);
    }
    __syncthreads();

    // ---- attn-out projection (weights broadcast from LDS) ----
    float f[64];
    #pragma unroll
    for (int c = 0; c < 64; ++c) f[c] = b_attn[c];
    for (int kc = 0; kc < 4; ++kc) {
        float o16[16];
        const float4* os = (const float4*)(outb + (size_t)i * 64 + kc*16);
        #pragma unroll
        for (int q = 0; q < 4; ++q) {
            float4 t = os[q];
            o16[4*q]=t.x; o16[4*q+1]=t.y; o16[4*q+2]=t.z; o16[4*q+3]=t.w;
        }
        #pragma unroll
        for (int j = 0; j < 16; ++j) {
            float vv = o16[j];
            int row = kc*16 + j;
            #pragma unroll
            for (int c4 = 0; c4 < 16; ++c4) {
                float4 w = *(const float4*)&sWa[row*64 + c4*4];
                FMA4(f, c4*4, w);
            }
        }
    }
    // + residual feat
    {
        const float4* fs = (const float4*)(featb + (size_t)i * 64);
        #pragma unroll
        for (int c4 = 0; c4 < 16; ++c4) {
            float4 t = fs[c4];
            f[4*c4]+=t.x; f[4*c4+1]+=t.y; f[4*c4+2]+=t.z; f[4*c4+3]+=t.w;
        }
    }
    // LN2 -> hh (read-only hereafter; f is the FFN accumulator)
    float hh[64];
    {
        float s0 = 0.f;
        #pragma unroll
        for (int c = 0; c < 64; ++c) s0 += f[c];
        float m = s0 * (1.f/64.f);
        float v0 = 0.f;
        #pragma unroll
        for (int c = 0; c < 64; ++c) { float d = f[c]-m; v0 = fmaf(d, d, v0); }
        float rs = 1.f / sqrtf(v0 * (1.f/64.f) + 1e-5f);
        #pragma unroll
        for (int c = 0; c < 64; ++c) hh[c] = (f[c]-m)*rs*g2[c] + be2[c];
    }
    // ---- FFN: f += gelu(hh@W_f1+b_f1) @ W_f2 + b_f2, 16 chunks dbuf ----
    #pragma unroll
    for (int c = 0; c < 64; ++c) f[c] += b_f2[c];
    int cur = 0;
    for (int ch = 0; ch < 16; ++ch) {
        bool have = (ch + 1 < 16);
        float4 nw1, nw2;
        if (have) {
            nw1 = *(const float4*)(W_f1 + (size_t)sc*256 + (ch+1)*16 + st4*4);
            nw2 = *(const float4*)(W_f2 + ((size_t)(ch+1)*16 + stt)*64 + sc4*4);
        }
        float a[16];
        #pragma unroll
        for (int t = 0; t < 16; ++t) a[t] = b_f1[ch*16 + t];
        #pragma unroll
        for (int c = 0; c < 64; ++c) {
            float vv = hh[c];
            #pragma unroll
            for (int q = 0; q < 4; ++q) {
                float4 w = *(const float4*)&sW1[cur][c][q*4];
                FMA4(a, q*4, w);
            }
        }
        #pragma unroll
        for (int t = 0; t < 16; ++t) a[t] = gelu_exact(a[t]);
        #pragma unroll
        for (int t = 0; t < 16; ++t) {
            float vv = a[t];
            #pragma unroll
            for (int c4 = 0; c4 < 16; ++c4) {
                float4 w = *(const float4*)&sW2[cur][t][c4*4];
                FMA4(f, c4*4, w);
            }
        }
        __syncthreads();
        if (have) {
            *(float4*)&sW1[cur ^ 1][sc][st4*4] = nw1;
            *(float4*)&sW2[cur ^ 1][stt][sc4*4] = nw2;
        }
        __syncthreads();
        cur ^= 1;
    }
    // ---- head: gelu(f @ W_h1 + b_h1) @ W_h2 + b_h2 ----
    float g[32];
    #pragma unroll
    for (int t = 0; t < 32; ++t) g[t] = 0.f;
    #pragma unroll
    for (int c = 0; c < 64; ++c) {
        float vv = f[c];
        #pragma unroll
        for (int q = 0; q < 8; ++q) {
            float4 w = *(const float4*)&sH1[c*32 + q*4];
            FMA4(g, q*4, w);
        }
    }
    #pragma unroll
    for (int t = 0; t < 32; ++t) g[t] = gelu_exact(g[t] + b_h1[t]);
    float r0 = b_h2[0], r1 = b_h2[1], r2 = b_h2[2];
    #pragma unroll
    for (int t = 0; t < 32; ++t) {
        float gv = g[t];
        r0 = fmaf(gv, W_h2[t*3 + 0], r0);
        r1 = fmaf(gv, W_h2[t*3 + 1], r1);
        r2 = fmaf(gv, W_h2[t*3 + 2], r2);
    }
    out[(size_t)i*3 + 0] = r0;
    out[(size_t)i*3 + 1] = r1;
    out[(size_t)i*3 + 2] = r2;
}

// ---------------------------------------------------------------------------
extern "C" void kernel_launch(void* const* d_in, const int* in_sizes, int n_in,
                              void* d_out, int out_size, void* d_ws, size_t ws_size,
                              hipStream_t stream)
{
    const float* seg    = (const float*)d_in[0];
    const float* coord  = (const float*)d_in[1];
    const int*   order  = (const int*)d_in[2];
    const int*   gc     = (const int*)d_in[4];
    const float* W_in   = (const float*)d_in[5];
    const float* b_in   = (const float*)d_in[6];
    const float* g1     = (const float*)d_in[7];
    const float* be1    = (const float*)d_in[8];
    const float* W_qkv  = (const float*)d_in[9];
    const float* b_qkv  = (const float*)d_in[10];
    const float* rpe    = (const float*)d_in[11];
    const float* W_attn = (const float*)d_in[12];
    const float* b_attn = (const float*)d_in[13];
    const float* g2     = (const float*)d_in[14];
    const float* be2    = (const float*)d_in[15];
    const float* W_f1   = (const float*)d_in[16];
    const float* b_f1   = (const float*)d_in[17];
    const float* W_f2   = (const float*)d_in[18];
    const float* b_f2   = (const float*)d_in[19];
    const float* W_h1   = (const float*)d_in[20];
    const float* b_h1   = (const float*)d_in[21];
    const float* W_h2   = (const float*)d_in[22];
    const float* b_h2   = (const float*)d_in[23];

    // workspace: feat[N*64] | qkv[N*192] | attn_out[N*64]  (fp32)
    float* feat = (float*)d_ws;
    float* qkvb = feat + (size_t)N_PTS * 64;
    float* outw = qkvb + (size_t)N_PTS * 192;

    k_in_qkv<<<N_PTS/256, 256, 0, stream>>>(seg, coord, W_in, b_in, g1, be1,
                                            W_qkv, b_qkv, feat, qkvb);
    k_attn<<<NPATCH, 256, 0, stream>>>(qkvb, order, gc, rpe, outw);
    k_ffn<<<N_PTS/256, 256, 0, stream>>>(outw, feat, W_attn, b_attn, g2, be2,
                                         W_f1, b_f1, W_f2, b_f2,
                                         W_h1, b_h1, W_h2, b_h2, (float*)d_out);
}